// Round 12
// baseline (154.965 us; speedup 1.0000x reference)
//
#include <hip/hip_runtime.h>
#include <hip/hip_bf16.h>
#include <math.h>

#define BB 8
#define NQ 1024
#define NKV 2048
#define DIM 512
#define H 8
#define DH 64
#define INNER 512
// 0.125 * log2(e): folded into Q so QK^T scores feed v_exp_f32 (2^x) directly
#define SCALE_LOG2E 0.18033688011112042f

typedef __bf16 bf16x8 __attribute__((ext_vector_type(8)));
typedef float f32x4 __attribute__((ext_vector_type(4)));
typedef unsigned int u32x4 __attribute__((ext_vector_type(4)));

__device__ __forceinline__ unsigned short f2bf(float f) {
  union { float f; unsigned int u; } v; v.f = f;
  unsigned int r = v.u + 0x7fffu + ((v.u >> 16) & 1u);
  return (unsigned short)(r >> 16);
}
__device__ __forceinline__ float bf2f(unsigned short h) {
  union { unsigned int u; float f; } v; v.u = ((unsigned int)h) << 16;
  return v.f;
}

// async global->LDS, 16B per lane. LDS dest = wave-uniform base + lane*16 (linear).
__device__ __forceinline__ void gl_lds16(const unsigned short* g, unsigned short* l) {
  __builtin_amdgcn_global_load_lds(
      (const __attribute__((address_space(1))) unsigned int*)g,
      (__attribute__((address_space(3))) unsigned int*)l, 16, 0, 0);
}

// ---------------- K_A: fused LN (blocks 0..2047, 12 rows each) +
//                  weight cast/transpose (blocks 2048..2303) ----------------
__global__ __launch_bounds__(256) void prep_ln(
    const float* __restrict__ Wq, const float* __restrict__ Wkv,
    const float* __restrict__ Wo,
    unsigned short* __restrict__ WqT, unsigned short* __restrict__ WkvT,
    unsigned short* __restrict__ WohT, unsigned short* __restrict__ WolT,
    const float* __restrict__ xq, const float* __restrict__ xc,
    const float* __restrict__ gq, const float* __restrict__ bq,
    const float* __restrict__ gc, const float* __restrict__ bc,
    unsigned short* __restrict__ xq_bf, unsigned short* __restrict__ xc_bf) {
  __shared__ float T[64][65];
  __shared__ float red[8];
  int blk = blockIdx.x;
  int t = threadIdx.x;
  if (blk < 2048) {
    // ---- LayerNorm path: 12 rows per block ----
    int wid = t >> 6, lane = t & 63;
    for (int rr = 0; rr < 12; ++rr) {
      int row = blk * 12 + rr;     // 0..24575
      const float* x; const float* g; const float* bbv; unsigned short* outp;
      if (row < BB * NQ) {
        x = xq + (size_t)row * DIM; g = gq; bbv = bq; outp = xq_bf + (size_t)row * DIM;
      } else {
        int r2 = row - BB * NQ;
        x = xc + (size_t)r2 * DIM; g = gc; bbv = bc; outp = xc_bf + (size_t)r2 * DIM;
      }
      float2 v = *reinterpret_cast<const float2*>(x + t * 2);
      float s = v.x + v.y;
      float ss = v.x * v.x + v.y * v.y;
#pragma unroll
      for (int d = 1; d < 64; d <<= 1) { s += __shfl_xor(s, d); ss += __shfl_xor(ss, d); }
      if (lane == 0) { red[wid] = s; red[4 + wid] = ss; }
      __syncthreads();
      s = red[0] + red[1] + red[2] + red[3];
      ss = red[4] + red[5] + red[6] + red[7];
      __syncthreads();   // protect red before next row's write
      float mu = s * (1.0f / DIM);
      float var = ss * (1.0f / DIM) - mu * mu;
      float rs = rsqrtf(var + 1e-5f);
      float y0 = (v.x - mu) * rs * g[t * 2] + bbv[t * 2];
      float y1 = (v.y - mu) * rs * g[t * 2 + 1] + bbv[t * 2 + 1];
      ushort2 o; o.x = f2bf(y0); o.y = f2bf(y1);
      *reinterpret_cast<ushort2*>(outp + t * 2) = o;
    }
  } else {
    // ---- weight prep path ----
    int blk2 = blk - 2048;
    const float* src; int Wd, ti, tj, mode;
    unsigned short* dst = nullptr;
    if (blk2 < 64) { src = Wq;  dst = WqT;  Wd = 512;  ti = blk2 >> 3; tj = blk2 & 7; mode = 0; }
    else if (blk2 < 192) { int b2 = blk2 - 64; src = Wkv; dst = WkvT; Wd = 1024; ti = b2 >> 4; tj = b2 & 15; mode = 0; }
    else { int b2 = blk2 - 192; src = Wo; Wd = 512; ti = b2 >> 3; tj = b2 & 7; mode = 1; }
#pragma unroll
    for (int i = 0; i < 16; ++i) {
      int idx = i * 256 + t;
      int r = idx >> 6, c = idx & 63;
      T[r][c] = src[(size_t)(ti * 64 + r) * Wd + tj * 64 + c];
    }
    __syncthreads();
#pragma unroll
    for (int i = 0; i < 16; ++i) {
      int idx = i * 256 + t;
      int n = idx >> 6, k = idx & 63;
      float v = T[k][n];
      size_t off = (size_t)(tj * 64 + n) * 512 + ti * 64 + k;
      if (mode == 0) {
        dst[off] = f2bf(v);
      } else {
        unsigned short hb = f2bf(v);
        WohT[off] = hb;
        WolT[off] = f2bf(v - bf2f(hb));
      }
    }
  }
}

// ---------------- 128x128 MFMA mainloop, 2-PHASE double-buffered staging ----------------
// T3-minimum recipe: issue tile s+1's global_load_lds into buf[cur^1] BEFORE
// computing tile s from buf[cur]; ONE barrier per K-step (its vmcnt(0) drain
// lands the prefetch). Loads fly under the MFMAs instead of being serially
// drained before compute (the old 0-phase structure exposed the full L2/HBM
// flight 8x per block). Safety: stage(s+1) writes buf[cur^1], whose last
// readers (compute s-1) all passed barrier(s-1) before any wave enters iter s.
// LDS: 4 x 16KB buffers = 64KB -> 2 blocks/CU.
__device__ __forceinline__ void gemm128_mainloop(
    const unsigned short* __restrict__ A, const unsigned short* __restrict__ WT,
    char* smem, int rowBase, int colBase, f32x4 acc[4][4]) {
  const int t = threadIdx.x;
  const int w = t >> 6, l = t & 63;
  const int l15 = l & 15, lg = l >> 4, c7 = l15 & 7;
  const int wr = w >> 1, wc = w & 1;
  const int lrow = l >> 3;                 // 0..7 within a 1KB segment
  const int lchunk = (l & 7) ^ lrow;       // pre-swizzled global 16B chunk
  const int frag = (lg ^ c7) * 8;
  const unsigned short* Ag = A + (size_t)rowBase * 512;
  const unsigned short* Wg = WT + (size_t)colBase * 512;
  unsigned short* AsB[2] = { (unsigned short*)smem, (unsigned short*)(smem + 32768) };
  unsigned short* WsB[2] = { (unsigned short*)(smem + 16384), (unsigned short*)(smem + 49152) };
#pragma unroll
  for (int m = 0; m < 4; ++m)
#pragma unroll
    for (int n = 0; n < 4; ++n) acc[m][n] = f32x4{0.f, 0.f, 0.f, 0.f};
  // prologue: stage tile 0 into buf0
#pragma unroll
  for (int i = 0; i < 4; ++i) {
    const int seg = w * 4 + i;
    const size_t goff = (size_t)(seg * 8 + lrow) * 512 + lchunk * 8;
    gl_lds16(Ag + goff, AsB[0] + seg * 512);
    gl_lds16(Wg + goff, WsB[0] + seg * 512);
  }
  __syncthreads();   // drains vmcnt(0): tile 0 resident
  for (int s = 0; s < 8; ++s) {
    const int cur = s & 1;
    // issue next tile's loads into the other buffer — in flight during MFMA
    if (s + 1 < 8) {
#pragma unroll
      for (int i = 0; i < 4; ++i) {
        const int seg = w * 4 + i;
        const size_t goff = (size_t)(seg * 8 + lrow) * 512 + (s + 1) * 64 + lchunk * 8;
        gl_lds16(Ag + goff, AsB[cur ^ 1] + seg * 512);
        gl_lds16(Wg + goff, WsB[cur ^ 1] + seg * 512);
      }
    }
    const unsigned short* As = AsB[cur];
    const unsigned short* Ws = WsB[cur];
#pragma unroll
    for (int ks = 0; ks < 2; ++ks) {
      const int xo = ks ? 32 : 0;
      bf16x8 af[4], bf_[4];
#pragma unroll
      for (int m = 0; m < 4; ++m)
        af[m] = *reinterpret_cast<const bf16x8*>(
            &As[(wr * 64 + m * 16 + l15) * 64 + (frag ^ xo)]);
#pragma unroll
      for (int n = 0; n < 4; ++n)
        bf_[n] = *reinterpret_cast<const bf16x8*>(
            &Ws[(wc * 64 + n * 16 + l15) * 64 + (frag ^ xo)]);
#pragma unroll
      for (int m = 0; m < 4; ++m)
#pragma unroll
        for (int n = 0; n < 4; ++n)
          acc[m][n] = __builtin_amdgcn_mfma_f32_16x16x32_bf16(af[m], bf_[n], acc[m][n], 0, 0, 0);
    }
    __syncthreads();   // drains vmcnt(0) -> next tile resident; syncs buffer swap
  }
}

// ---------------- K_B: fused projections ----------------
// blocks 0..1023: kv 128x128 tiles (K masked+rotary, V sigma image masked)
// blocks 1024..1279: q 128x128 tiles (rotary + scale*log2e)
// V epilogue is TWO-PASS: pass A applies rotary+mask in coalesced K-path
// order writing back into Cs; pass B permutes/packs from LDS only.
__global__ __launch_bounds__(256) void proj_fused(
    const unsigned short* __restrict__ xq_bf, const unsigned short* __restrict__ xc_bf,
    const unsigned short* __restrict__ WqT, const unsigned short* __restrict__ WkvT,
    const float* __restrict__ rotq, const float* __restrict__ rotc,
    const int* __restrict__ cmask,
    unsigned short* __restrict__ Qb, unsigned short* __restrict__ Kb,
    unsigned short* __restrict__ VTb) {
  __shared__ __align__(16) char smem[65536];   // 2-phase staging; Cs unions base
  float (*Cs)[66] = (float(*)[66])smem;
  const int t = threadIdx.x;
  const int w = t >> 6, l = t & 63;
  const int l15 = l & 15, lg = l >> 4;
  const int wr = w >> 1, wc = w & 1;
  f32x4 acc[4][4];
  int o = blockIdx.x;
  if (o < 1024) {
    // ================= kv path =================
    int swz = ((o & 7) << 7) | (o >> 3);
    int bn = swz & 7, bm = swz >> 3;     // bn: 128-col group (0..7), bm: 128-row group
    gemm128_mainloop(xc_bf, WkvT, smem, bm * 128, bn * 128, acc);
#pragma unroll
    for (int hc = 0; hc < 2; ++hc) {
      if (wc == hc) {
#pragma unroll
        for (int m = 0; m < 4; ++m)
#pragma unroll
          for (int n = 0; n < 4; ++n)
#pragma unroll
            for (int r = 0; r < 4; ++r)
              Cs[wr * 64 + m * 16 + lg * 4 + r][n * 16 + l15] = acc[m][n][r];
      }
      __syncthreads();
      const int g = bn * 2 + hc;           // 64-col group 0..15
      const int h = g & 7;
      if (g < 8) {
        // K path: rotary+mask, coalesced, direct store
#pragma unroll
        for (int i = 0; i < 16; ++i) {
          int p = i * 256 + t;
          int row = p >> 5, pc = p & 31, d0 = pc * 2;
          int grow = bm * 128 + row;         // b*NKV + kv
          float c0 = Cs[row][d0], c1 = Cs[row][d0 + 1];
          const float* f = rotc + (size_t)grow * DH + d0;
          float f0 = f[0], f1 = f[1], s0, s1, co0, co1;
          __sincosf(f0, &s0, &co0);
          __sincosf(f1, &s1, &co1);
          float mf = cmask[grow] ? 1.f : 0.f;
          float o0 = (c0 * co0 - c1 * s0) * mf;
          float o1 = (c1 * co1 + c0 * s1) * mf;
          int b = grow >> 11, kk = grow & 2047;
          ushort2 ov; ov.x = f2bf(o0); ov.y = f2bf(o1);
          *reinterpret_cast<ushort2*>(Kb + (((size_t)(b * H + h) * NKV + kk) * DH + d0)) = ov;
        }
      } else {
        // V pass A: rotary+mask in coalesced K-path order, write back to Cs
#pragma unroll
        for (int i = 0; i < 16; ++i) {
          int p = i * 256 + t;
          int row = p >> 5, pc = p & 31, d0 = pc * 2;
          int grow = bm * 128 + row;
          float c0 = Cs[row][d0], c1 = Cs[row][d0 + 1];
          const float* f = rotc + (size_t)grow * DH + d0;
          float f0 = f[0], f1 = f[1], s0, s1, co0, co1;
          __sincosf(f0, &s0, &co0);
          __sincosf(f1, &s1, &co1);
          float mf = cmask[grow] ? 1.f : 0.f;
          Cs[row][d0]     = (c0 * co0 - c1 * s0) * mf;
          Cs[row][d0 + 1] = (c1 * co1 + c0 * s1) * mf;
        }
        __syncthreads();
        // V pass B: permute/pack from LDS only (no global loads, no sincos)
        int oc = t & 7;          // position octet
        int dd0 = t >> 3;        // 0..31
#pragma unroll
        for (int ch = 0; ch < 2; ++ch) {
          int ch64 = bm * 2 + ch;            // global 64-row chunk index
          int bb = ch64 >> 5, chunk = ch64 & 31;
          unsigned short* vbase = VTb + (((size_t)(bb * H + h) * 32 + chunk) * 64) * 64;
#pragma unroll
          for (int half = 0; half < 2; ++half) {
            int d = dd0 + half * 32;
            u32x4 pack;
#pragma unroll
            for (int j2 = 0; j2 < 4; ++j2) {
              unsigned int lohi[2];
#pragma unroll
              for (int e = 0; e < 2; ++e) {
                int p = oc * 8 + j2 * 2 + e;
                int pp = p & 31;
                int kv = (p >> 5) * 32 + ((pp & 1) ? ((pp >> 1) + 16) : (pp >> 1));
                lohi[e] = f2bf(Cs[ch * 64 + kv][d]);
              }
              pack[j2] = lohi[0] | (lohi[1] << 16);
            }
            *reinterpret_cast<u32x4*>(vbase + d * 64 + oc * 8) = pack;
          }
        }
      }
      __syncthreads();
    }
  } else {
    // ================= q path: 128x128 tiles =================
    int o2 = o - 1024;
    int swz = ((o2 & 7) << 5) | (o2 >> 3);
    int bn = swz & 3, bm = swz >> 2;     // bn: 128-col group (2 heads), bm: 128-row group
    gemm128_mainloop(xq_bf, WqT, smem, bm * 128, bn * 128, acc);
#pragma unroll
    for (int hc = 0; hc < 2; ++hc) {
      if (wc == hc) {
#pragma unroll
        for (int m = 0; m < 4; ++m)
#pragma unroll
          for (int n = 0; n < 4; ++n)
#pragma unroll
            for (int r = 0; r < 4; ++r)
              Cs[wr * 64 + m * 16 + lg * 4 + r][n * 16 + l15] = acc[m][n][r];
      }
      __syncthreads();
      const int head = bn * 2 + hc;
#pragma unroll
      for (int i = 0; i < 16; ++i) {
        int p = i * 256 + t;
        int row = p >> 5, pc = p & 31, d0 = pc * 2;
        int grow = bm * 128 + row;           // b*NQ + q
        float c0 = Cs[row][d0], c1 = Cs[row][d0 + 1];
        const float* f = rotq + (size_t)grow * DH + d0;
        float f0 = f[0], f1 = f[1], s0, s1, co0, co1;
        __sincosf(f0, &s0, &co0);
        __sincosf(f1, &s1, &co1);
        float o0 = (c0 * co0 - c1 * s0) * SCALE_LOG2E;
        float o1 = (c1 * co1 + c0 * s1) * SCALE_LOG2E;
        ushort2 ov; ov.x = f2bf(o0); ov.y = f2bf(o1);
        int b = grow >> 10, qq = grow & 1023;
        *reinterpret_cast<ushort2*>(Qb + (((size_t)(b * H + head) * NQ + qq) * DH + d0)) = ov;
      }
      __syncthreads();
    }
  }
}

// ---------------- K4: flash attention -> hi/lo bf16 split output ----------------
// Swapped QK^T (mfma(K,Q) -> P^T): lane (lg,l15) holds P[q=w*16+l15]
// [kv=tt*16+lg*4+r] in registers. The V sigma image stores position pairs
// (2c,2c+1) <- kv (c,c+16) within each 32-block, so the PV A-fragment is
// assembled IN-LANE: pa.u[i] = cvt_pk(p[ks*2][i], p[ks*2+1][i]) — zero
// shuffles, zero LDS for P (8KB freed), no lgkmcnt drain.
// Double-buffered K/V, one barrier per tile. Mask pre-applied to K/V in
// proj; denominator corrected by n_masked.
__global__ __launch_bounds__(256) void attn_kernel(
    const unsigned short* __restrict__ Qb, const unsigned short* __restrict__ Kb,
    const unsigned short* __restrict__ VTb, const int* __restrict__ mask,
    const float* __restrict__ rotq,
    unsigned short* __restrict__ Ahb, unsigned short* __restrict__ Alb) {
  __shared__ unsigned short Ks[2 * 64 * 64];
  __shared__ unsigned short Vs[2 * 64 * 64];
  int ob = blockIdx.x;
  int swz = ((ob & 7) << 7) + (ob >> 3);
  int qb = swz & 15;
  int bh = swz >> 4;
  int b = bh >> 3, hh = bh & 7;
  int t = threadIdx.x, w = t >> 6, l = t & 63;
  int l15 = l & 15, lg = l >> 4;
  int c7 = l15 & 7;

  // n_masked: each wave redundantly popcounts the 8KB mask row (L2-hot, once)
  float nmasked;
  {
    const int* mrow = mask + b * NKV;
    float msum = 0.f;
#pragma unroll
    for (int i = 0; i < 8; ++i) {
      int4 m = *reinterpret_cast<const int4*>(mrow + l * 4 + i * 256);
      msum += (m.x ? 1.f : 0.f) + (m.y ? 1.f : 0.f) +
              (m.z ? 1.f : 0.f) + (m.w ? 1.f : 0.f);
    }
#pragma unroll
    for (int d = 1; d < 64; d <<= 1) msum += __shfl_xor(msum, d);
    nmasked = (float)NKV - msum;
  }

  const unsigned short* qrow = Qb + ((size_t)bh * NQ + qb * 64 + w * 16 + l15) * DH;
  bf16x8 qa0 = *reinterpret_cast<const bf16x8*>(qrow + lg * 8);
  bf16x8 qa1 = *reinterpret_cast<const bf16x8*>(qrow + 32 + lg * 8);

  float plsum = 0.f;
  f32x4 acc[4];
#pragma unroll
  for (int ct = 0; ct < 4; ++ct) acc[ct] = f32x4{0.f, 0.f, 0.f, 0.f};

  const int srow = t >> 2;
  const int sseg = (t & 3) * 16;
  const int sdst0 = srow * 64 + ((2 * (t & 3)) ^ (srow & 7)) * 8;
  const int frag = (lg ^ c7) * 8;
  const int kbase = l15 * 64 + frag;

  const unsigned short* gk = Kb + ((size_t)bh * NKV + srow) * DH + sseg;
  const unsigned short* gv = VTb + (((size_t)bh * 32) * 64 + srow) * 64 + sseg;

  // prologue: prefetch tile 0 into registers
  bf16x8 kr0 = *reinterpret_cast<const bf16x8*>(gk);
  bf16x8 kr1 = *reinterpret_cast<const bf16x8*>(gk + 8);
  bf16x8 vr0 = *reinterpret_cast<const bf16x8*>(gv);
  bf16x8 vr1 = *reinterpret_cast<const bf16x8*>(gv + 8);
  gk += 4096; gv += 4096;

#pragma unroll 2
  for (int ic = 0; ic < NKV / 64; ++ic) {
    const int bo_ = (ic & 1) << 12;   // double-buffer offset in shorts
    *reinterpret_cast<bf16x8*>(&Ks[bo_ + sdst0])       = kr0;
    *reinterpret_cast<bf16x8*>(&Ks[bo_ + (sdst0 ^ 8)]) = kr1;
    *reinterpret_cast<bf16x8*>(&Vs[bo_ + sdst0])       = vr0;
    *reinterpret_cast<bf16x8*>(&Vs[bo_ + (sdst0 ^ 8)]) = vr1;
    __syncthreads();
    if (ic + 1 < NKV / 64) {
      kr0 = *reinterpret_cast<const bf16x8*>(gk);
      kr1 = *reinterpret_cast<const bf16x8*>(gk + 8);
      vr0 = *reinterpret_cast<const bf16x8*>(gv);
      vr1 = *reinterpret_cast<const bf16x8*>(gv + 8);
      gk += 4096; gv += 4096;
    }
    // SWAPPED QK^T: mfma(K, Q) -> lane: q = l15, kv = tt*16 + lg*4 + r
    f32x4 s[4];
    __builtin_amdgcn_s_setprio(1);
#pragma unroll
    for (int tt = 0; tt < 4; ++tt) {
      f32x4 z = f32x4{0.f, 0.f, 0.f, 0.f};
      bf16x8 k0 = *reinterpret_cast<const bf16x8*>(&Ks[bo_ + tt * 1024 + kbase]);
      z = __builtin_amdgcn_mfma_f32_16x16x32_bf16(k0, qa0, z, 0, 0, 0);
      bf16x8 k1 = *reinterpret_cast<const bf16x8*>(&Ks[bo_ + tt * 1024 + (kbase ^ 32)]);
      z = __builtin_amdgcn_mfma_f32_16x16x32_bf16(k1, qa1, z, 0, 0, 0);
      s[tt] = z;
    }
    __builtin_amdgcn_s_setprio(0);
    // softmax: exp2; row (q) partial sum is lane-local
    float p[4][4];
#pragma unroll
    for (int tt = 0; tt < 4; ++tt)
#pragma unroll
      for (int r = 0; r < 4; ++r) {
        float e;
        asm("v_exp_f32 %0, %1" : "=v"(e) : "v"(s[tt][r]));
        p[tt][r] = e;
      }
    plsum += ((p[0][0] + p[0][1]) + (p[0][2] + p[0][3])) +
             ((p[1][0] + p[1][1]) + (p[1][2] + p[1][3])) +
             ((p[2][0] + p[2][1]) + (p[2][2] + p[2][3])) +
             ((p[3][0] + p[3][1]) + (p[3][2] + p[3][3]));
    // PV: A-fragment assembled IN-LANE. V position perm within each 32-block
    // is (2c,2c+1) <- kv (c,c+16); element e of the ks-fragment needs
    // kv = ks*32 + 16*(e&1) + lg*4 + (e>>1) = p[ks*2+(e&1)][e>>1]. So:
    __builtin_amdgcn_s_setprio(1);
#pragma unroll
    for (int ks = 0; ks < 2; ++ks) {
      union { u32x4 u; bf16x8 b; } pa;
#pragma unroll
      for (int i = 0; i < 4; ++i)
        asm("v_cvt_pk_bf16_f32 %0, %1, %2"
            : "=v"(pa.u[i]) : "v"(p[ks * 2][i]), "v"(p[ks * 2 + 1][i]));
#pragma unroll
      for (int ct = 0; ct < 4; ++ct) {
        bf16x8 vb = *reinterpret_cast<const bf16x8*>(
            &Vs[bo_ + ct * 1024 + (kbase ^ (ks ? 32 : 0))]);
        acc[ct] = __builtin_amdgcn_mfma_f32_16x16x32_bf16(pa.b, vb, acc[ct], 0, 0, 0);
      }
    }
    __builtin_amdgcn_s_setprio(0);
  }
  // reduce plsum across the 4 lane-groups (same l15 = same q)
  plsum += __shfl_xor(plsum, 16);
  plsum += __shfl_xor(plsum, 32);
  float inv[4];
#pragma unroll
  for (int r = 0; r < 4; ++r)
    inv[r] = 1.0f / (__shfl(plsum, lg * 4 + r) - nmasked);

  int q0 = qb * 64 + w * 16 + lg * 4;
#pragma unroll
  for (int r = 0; r < 4; ++r) {
    int grow = b * NQ + q0 + r;
    const float* frow = rotq + (size_t)grow * DH;
    size_t obase = (size_t)grow * INNER + hh * DH;
#pragma unroll
    for (int ct = 0; ct < 4; ++ct) {
      int d = ct * 16 + l15;
      float x = acc[ct][r] * inv[r];
      float nb = __shfl_xor(x, 1);
      float f = frow[d];
      float sn, cs;
      __sincosf(f, &sn, &cs);
      float ov = (d & 1) ? (x * cs - nb * sn) : (x * cs + nb * sn);
      unsigned short hb = f2bf(ov);
      Ahb[obase + d] = hb;
      Alb[obase + d] = f2bf(ov - bf2f(hb));
    }
  }
}

// ---------------- K_D: final GEMM, bf16 hi/lo split (3-term), 128x64 tiles ----------------
// out = Ah*Wh + Al*Wh + Ah*Wl + bias   (Al*Wl dropped, ~2^-18 relative)
// 512 blocks -> 2 blocks/CU. Tile grid: 64 row-groups x 8 col-groups.
__global__ __launch_bounds__(256) void final_gemm(
    const unsigned short* __restrict__ Ah, const unsigned short* __restrict__ Al,
    const unsigned short* __restrict__ Wh, const unsigned short* __restrict__ Wl,
    const float* __restrict__ bo, float* __restrict__ out) {
  __shared__ __align__(16) char smem[49152];
  unsigned short* AhS = (unsigned short*)smem;            // 128x64
  unsigned short* AlS = (unsigned short*)(smem + 16384);  // 128x64
  unsigned short* WhS = (unsigned short*)(smem + 32768);  //  64x64
  unsigned short* WlS = (unsigned short*)(smem + 40960);  //  64x64
  int o = blockIdx.x;                    // 512 blocks
  int swz = ((o & 7) << 6) | (o >> 3);
  int bn = swz & 7, bm = swz >> 3;       // bn: 64-col group (0..7), bm: 128-row group (0..63)
  const int t = threadIdx.x;
  const int w = t >> 6, l = t & 63;
  const int l15 = l & 15, lg = l >> 4, c7 = l15 & 7;
  const int wr = w >> 1, wc = w & 1;
  const int lrow = l >> 3;
  const int lchunk = (l & 7) ^ lrow;
  const int frag = (lg ^ c7) * 8;
  const unsigned short* Agh = Ah + (size_t)bm * 128 * 512;
  const unsigned short* Agl = Al + (size_t)bm * 128 * 512;
  const unsigned short* Wgh = Wh + (size_t)bn * 64 * 512;
  const unsigned short* Wgl = Wl + (size_t)bn * 64 * 512;
  f32x4 acc[4][2];
#pragma unroll
  for (int m = 0; m < 4; ++m)
#pragma unroll
    for (int n = 0; n < 2; ++n) acc[m][n] = f32x4{0.f, 0.f, 0.f, 0.f};
  for (int kb = 0; kb < 512; kb += 64) {
#pragma unroll
    for (int i = 0; i < 4; ++i) {
      const int seg = w * 4 + i;                       // 16 segs of 8 rows (A: 128 rows)
      const size_t goff = (size_t)(seg * 8 + lrow) * 512 + kb + lchunk * 8;
      gl_lds16(Agh + goff, AhS + seg * 512);
      gl_lds16(Agl + goff, AlS + seg * 512);
    }
#pragma unroll
    for (int i = 0; i < 2; ++i) {
      const int seg = w * 2 + i;                       // 8 segs of 8 rows (W: 64 rows)
      const size_t goff = (size_t)(seg * 8 + lrow) * 512 + kb + lchunk * 8;
      gl_lds16(Wgh + goff, WhS + seg * 512);
      gl_lds16(Wgl + goff, WlS + seg * 512);
    }
    __syncthreads();
#pragma unroll
    for (int ks = 0; ks < 2; ++ks) {
      const int xo = ks ? 32 : 0;
      bf16x8 ah[4], al[4], wh[2], wl[2];
#pragma unroll
      for (int m = 0; m < 4; ++m) {
        const int off = (wr * 64 + m * 16 + l15) * 64 + (frag ^ xo);
        ah[m] = *reinterpret_cast<const bf16x8*>(&AhS[off]);
        al[m] = *reinterpret_cast<const bf16x8*>(&AlS[off]);
      }
#pragma unroll
      for (int n = 0; n < 2; ++n) {
        const int off = (wc * 32 + n * 16 + l15) * 64 + (frag ^ xo);
        wh[n] = *reinterpret_cast<const bf16x8*>(&WhS[off]);
        wl[n] = *reinterpret_cast<const bf16x8*>(&WlS[off]);
      }
#pragma unroll
      for (int m = 0; m < 4; ++m)
#pragma unroll
        for (int n = 0; n < 2; ++n) {
          acc[m][n] = __builtin_amdgcn_mfma_f32_16x16x32_bf16(ah[m], wh[n], acc[m][n], 0, 0, 0);
          acc[m][n] = __builtin_amdgcn_mfma_f32_16x16x32_bf16(al[m], wh[n], acc[m][n], 0, 0, 0);
          acc[m][n] = __builtin_amdgcn_mfma_f32_16x16x32_bf16(ah[m], wl[n], acc[m][n], 0, 0, 0);
        }
    }
    __syncthreads();
  }
  const int row0 = bm * 128 + wr * 64;
  const int col0 = bn * 64 + wc * 32;
#pragma unroll
  for (int m = 0; m < 4; ++m)
#pragma unroll
    for (int n = 0; n < 2; ++n) {
      int col = col0 + n * 16 + l15;
      float bv = bo[col];
#pragma unroll
      for (int r = 0; r < 4; ++r)
        out[(size_t)(row0 + m * 16 + lg * 4 + r) * 512 + col] = acc[m][n][r] + bv;
    }
}

extern "C" void kernel_launch(void* const* d_in, const int* in_sizes, int n_in,
                              void* d_out, int out_size, void* d_ws, size_t ws_size,
                              hipStream_t stream) {
  const float* x_query   = (const float*)d_in[0];
  const float* x_context = (const float*)d_in[1];
  const float* rot_q     = (const float*)d_in[2];
  const float* rot_c     = (const float*)d_in[3];
  const int*   cmask     = (const int*)d_in[4];
  const float* ln_q_g    = (const float*)d_in[5];
  const float* ln_q_b    = (const float*)d_in[6];
  const float* ln_c_g    = (const float*)d_in[7];
  const float* ln_c_b    = (const float*)d_in[8];
  const float* Wq        = (const float*)d_in[9];
  const float* Wkv       = (const float*)d_in[10];
  const float* Wo        = (const float*)d_in[11];
  const float* bo        = (const float*)d_in[12];
  float* out = (float*)d_out;

  char* ws = (char*)d_ws;
  unsigned short* xq_bf = (unsigned short*)(ws + 0);          // 8 MB
  unsigned short* xc_bf = (unsigned short*)(ws + 8388608);    // 16 MB
  unsigned short* Ahb   = (unsigned short*)(ws + 0);          // 8 MB (after projections)
  unsigned short* Alb   = (unsigned short*)(ws + 8388608);    // 8 MB (after proj)
  unsigned short* WqT   = (unsigned short*)(ws + 25165824);   // 0.5 MB
  unsigned short* WkvT  = (unsigned short*)(ws + 25690112);   // 1 MB
  unsigned short* Qb    = (unsigned short*)(ws + 26738688);   // 8 MB
  unsigned short* Kb    = (unsigned short*)(ws + 35127296);   // 16 MB
  unsigned short* VTb   = (unsigned short*)(ws + 51904512);   // 16 MB
  unsigned short* WohT  = (unsigned short*)(ws + 68681728);   // 0.5 MB
  unsigned short* WolT  = (unsigned short*)(ws + 69206016);   // 0.5 MB

  prep_ln<<<dim3(2304), dim3(256), 0, stream>>>(
      Wq, Wkv, Wo, WqT, WkvT, WohT, WolT,
      x_query, x_context, ln_q_g, ln_q_b, ln_c_g, ln_c_b, xq_bf, xc_bf);
  proj_fused<<<dim3(1280), dim3(256), 0, stream>>>(
      xq_bf, xc_bf, WqT, WkvT, rot_q, rot_c, cmask, Qb, Kb, VTb);
  attn_kernel<<<dim3(1024), dim3(256), 0, stream>>>(Qb, Kb, VTb, cmask, rot_q, Ahb, Alb);
  final_gemm<<<dim3(512), dim3(256), 0, stream>>>(Ahb, Alb, WohT, WolT, bo, out);
}

// Round 13
// 135.221 us; speedup vs baseline: 1.1460x; 1.1460x over previous
//
#include <hip/hip_runtime.h>
#include <hip/hip_bf16.h>
#include <math.h>

#define BB 8
#define NQ 1024
#define NKV 2048
#define DIM 512
#define H 8
#define DH 64
#define INNER 512
// 0.125 * log2(e): folded into Q so QK^T scores feed v_exp_f32 (2^x) directly
#define SCALE_LOG2E 0.18033688011112042f

typedef __bf16 bf16x8 __attribute__((ext_vector_type(8)));
typedef float f32x4 __attribute__((ext_vector_type(4)));
typedef unsigned int u32x4 __attribute__((ext_vector_type(4)));

__device__ __forceinline__ unsigned short f2bf(float f) {
  union { float f; unsigned int u; } v; v.f = f;
  unsigned int r = v.u + 0x7fffu + ((v.u >> 16) & 1u);
  return (unsigned short)(r >> 16);
}
__device__ __forceinline__ float bf2f(unsigned short h) {
  union { unsigned int u; float f; } v; v.u = ((unsigned int)h) << 16;
  return v.f;
}

// async global->LDS, 16B per lane. LDS dest = wave-uniform base + lane*16 (linear).
__device__ __forceinline__ void gl_lds16(const unsigned short* g, unsigned short* l) {
  __builtin_amdgcn_global_load_lds(
      (const __attribute__((address_space(1))) unsigned int*)g,
      (__attribute__((address_space(3))) unsigned int*)l, 16, 0, 0);
}

// ---------------- K_A: fused LN (blocks 0..2047, 12 rows each) +
//                  weight cast/transpose (blocks 2048..2303) ----------------
__global__ __launch_bounds__(256) void prep_ln(
    const float* __restrict__ Wq, const float* __restrict__ Wkv,
    const float* __restrict__ Wo,
    unsigned short* __restrict__ WqT, unsigned short* __restrict__ WkvT,
    unsigned short* __restrict__ WohT, unsigned short* __restrict__ WolT,
    const float* __restrict__ xq, const float* __restrict__ xc,
    const float* __restrict__ gq, const float* __restrict__ bq,
    const float* __restrict__ gc, const float* __restrict__ bc,
    unsigned short* __restrict__ xq_bf, unsigned short* __restrict__ xc_bf) {
  __shared__ float T[64][65];
  __shared__ float red[8];
  int blk = blockIdx.x;
  int t = threadIdx.x;
  if (blk < 2048) {
    // ---- LayerNorm path: 12 rows per block ----
    int wid = t >> 6, lane = t & 63;
    for (int rr = 0; rr < 12; ++rr) {
      int row = blk * 12 + rr;     // 0..24575
      const float* x; const float* g; const float* bbv; unsigned short* outp;
      if (row < BB * NQ) {
        x = xq + (size_t)row * DIM; g = gq; bbv = bq; outp = xq_bf + (size_t)row * DIM;
      } else {
        int r2 = row - BB * NQ;
        x = xc + (size_t)r2 * DIM; g = gc; bbv = bc; outp = xc_bf + (size_t)r2 * DIM;
      }
      float2 v = *reinterpret_cast<const float2*>(x + t * 2);
      float s = v.x + v.y;
      float ss = v.x * v.x + v.y * v.y;
#pragma unroll
      for (int d = 1; d < 64; d <<= 1) { s += __shfl_xor(s, d); ss += __shfl_xor(ss, d); }
      if (lane == 0) { red[wid] = s; red[4 + wid] = ss; }
      __syncthreads();
      s = red[0] + red[1] + red[2] + red[3];
      ss = red[4] + red[5] + red[6] + red[7];
      __syncthreads();   // protect red before next row's write
      float mu = s * (1.0f / DIM);
      float var = ss * (1.0f / DIM) - mu * mu;
      float rs = rsqrtf(var + 1e-5f);
      float y0 = (v.x - mu) * rs * g[t * 2] + bbv[t * 2];
      float y1 = (v.y - mu) * rs * g[t * 2 + 1] + bbv[t * 2 + 1];
      ushort2 o; o.x = f2bf(y0); o.y = f2bf(y1);
      *reinterpret_cast<ushort2*>(outp + t * 2) = o;
    }
  } else {
    // ---- weight prep path ----
    int blk2 = blk - 2048;
    const float* src; int Wd, ti, tj, mode;
    unsigned short* dst = nullptr;
    if (blk2 < 64) { src = Wq;  dst = WqT;  Wd = 512;  ti = blk2 >> 3; tj = blk2 & 7; mode = 0; }
    else if (blk2 < 192) { int b2 = blk2 - 64; src = Wkv; dst = WkvT; Wd = 1024; ti = b2 >> 4; tj = b2 & 15; mode = 0; }
    else { int b2 = blk2 - 192; src = Wo; Wd = 512; ti = b2 >> 3; tj = b2 & 7; mode = 1; }
#pragma unroll
    for (int i = 0; i < 16; ++i) {
      int idx = i * 256 + t;
      int r = idx >> 6, c = idx & 63;
      T[r][c] = src[(size_t)(ti * 64 + r) * Wd + tj * 64 + c];
    }
    __syncthreads();
#pragma unroll
    for (int i = 0; i < 16; ++i) {
      int idx = i * 256 + t;
      int n = idx >> 6, k = idx & 63;
      float v = T[k][n];
      size_t off = (size_t)(tj * 64 + n) * 512 + ti * 64 + k;
      if (mode == 0) {
        dst[off] = f2bf(v);
      } else {
        unsigned short hb = f2bf(v);
        WohT[off] = hb;
        WolT[off] = f2bf(v - bf2f(hb));
      }
    }
  }
}

// ---------------- 128x128 MFMA mainloop (m97 structure) ----------------
// 4 waves in 2x2, each owns a 64x64 quadrant (acc[4][4] f32x4).
// Staging: global_load_lds width=16, linear LDS dest, PRE-SWIZZLED global
// source (chunk ^= row&7) so the LDS image matches the conflict-free
// XOR-swizzled ds_read_b128 pattern. BK=64, 8 K-steps, 2 barriers each.
// NOTE (R11 lesson): 2-phase double-buffering (64KB LDS) halves residency
// to 2 blocks/CU and REGRESSES (54->78us, occ 17->10%) — cross-block TLP
// is the dominant latency hider here; keep 32KB / 4 blocks/CU.
__device__ __forceinline__ void gemm128_mainloop(
    const unsigned short* __restrict__ A, const unsigned short* __restrict__ WT,
    unsigned short* As, unsigned short* Ws,
    int rowBase, int colBase, f32x4 acc[4][4]) {
  const int t = threadIdx.x;
  const int w = t >> 6, l = t & 63;
  const int l15 = l & 15, lg = l >> 4, c7 = l15 & 7;
  const int wr = w >> 1, wc = w & 1;
  const int lrow = l >> 3;                 // 0..7 within a 1KB segment
  const int lchunk = (l & 7) ^ lrow;       // pre-swizzled global 16B chunk
  const int frag = (lg ^ c7) * 8;
  const unsigned short* Ag = A + (size_t)rowBase * 512;
  const unsigned short* Wg = WT + (size_t)colBase * 512;
#pragma unroll
  for (int m = 0; m < 4; ++m)
#pragma unroll
    for (int n = 0; n < 4; ++n) acc[m][n] = f32x4{0.f, 0.f, 0.f, 0.f};
  for (int kb = 0; kb < 512; kb += 64) {
#pragma unroll
    for (int i = 0; i < 4; ++i) {
      const int seg = w * 4 + i;                       // 16 segs of 8 rows
      const size_t goff = (size_t)(seg * 8 + lrow) * 512 + kb + lchunk * 8;
      gl_lds16(Ag + goff, As + seg * 512);
      gl_lds16(Wg + goff, Ws + seg * 512);
    }
    __syncthreads();   // drains vmcnt -> staged data visible
#pragma unroll
    for (int ks = 0; ks < 2; ++ks) {
      const int xo = ks ? 32 : 0;
      bf16x8 af[4], bf_[4];
#pragma unroll
      for (int m = 0; m < 4; ++m)
        af[m] = *reinterpret_cast<const bf16x8*>(
            &As[(wr * 64 + m * 16 + l15) * 64 + (frag ^ xo)]);
#pragma unroll
      for (int n = 0; n < 4; ++n)
        bf_[n] = *reinterpret_cast<const bf16x8*>(
            &Ws[(wc * 64 + n * 16 + l15) * 64 + (frag ^ xo)]);
#pragma unroll
      for (int m = 0; m < 4; ++m)
#pragma unroll
        for (int n = 0; n < 4; ++n)
          acc[m][n] = __builtin_amdgcn_mfma_f32_16x16x32_bf16(af[m], bf_[n], acc[m][n], 0, 0, 0);
    }
    __syncthreads();
  }
}

// ---------------- K_B: fused projections ----------------
// blocks 0..1023: kv 128x128 tiles (K masked+rotary, V sigma image masked)
// blocks 1024..1279: q 128x128 tiles (rotary + scale*log2e)
// V epilogue is TWO-PASS: pass A applies rotary+mask in coalesced K-path
// order writing back into Cs; pass B permutes/packs from LDS only.
__global__ __launch_bounds__(256) void proj_fused(
    const unsigned short* __restrict__ xq_bf, const unsigned short* __restrict__ xc_bf,
    const unsigned short* __restrict__ WqT, const unsigned short* __restrict__ WkvT,
    const float* __restrict__ rotq, const float* __restrict__ rotc,
    const int* __restrict__ cmask,
    unsigned short* __restrict__ Qb, unsigned short* __restrict__ Kb,
    unsigned short* __restrict__ VTb) {
  __shared__ __align__(16) char smem[128 * 66 * 4];   // staging (32KB) U Cs half (33KB)
  unsigned short* As = (unsigned short*)smem;
  unsigned short* Ws = (unsigned short*)(smem + 16384);
  float (*Cs)[66] = (float(*)[66])smem;
  const int t = threadIdx.x;
  const int w = t >> 6, l = t & 63;
  const int l15 = l & 15, lg = l >> 4;
  const int wr = w >> 1, wc = w & 1;
  f32x4 acc[4][4];
  int o = blockIdx.x;
  if (o < 1024) {
    // ================= kv path =================
    int swz = ((o & 7) << 7) | (o >> 3);
    int bn = swz & 7, bm = swz >> 3;     // bn: 128-col group (0..7), bm: 128-row group
    gemm128_mainloop(xc_bf, WkvT, As, Ws, bm * 128, bn * 128, acc);
#pragma unroll
    for (int hc = 0; hc < 2; ++hc) {
      if (wc == hc) {
#pragma unroll
        for (int m = 0; m < 4; ++m)
#pragma unroll
          for (int n = 0; n < 4; ++n)
#pragma unroll
            for (int r = 0; r < 4; ++r)
              Cs[wr * 64 + m * 16 + lg * 4 + r][n * 16 + l15] = acc[m][n][r];
      }
      __syncthreads();
      const int g = bn * 2 + hc;           // 64-col group 0..15
      const int h = g & 7;
      if (g < 8) {
        // K path: rotary+mask, coalesced, direct store
#pragma unroll
        for (int i = 0; i < 16; ++i) {
          int p = i * 256 + t;
          int row = p >> 5, pc = p & 31, d0 = pc * 2;
          int grow = bm * 128 + row;         // b*NKV + kv
          float c0 = Cs[row][d0], c1 = Cs[row][d0 + 1];
          const float* f = rotc + (size_t)grow * DH + d0;
          float f0 = f[0], f1 = f[1], s0, s1, co0, co1;
          __sincosf(f0, &s0, &co0);
          __sincosf(f1, &s1, &co1);
          float mf = cmask[grow] ? 1.f : 0.f;
          float o0 = (c0 * co0 - c1 * s0) * mf;
          float o1 = (c1 * co1 + c0 * s1) * mf;
          int b = grow >> 11, kk = grow & 2047;
          ushort2 ov; ov.x = f2bf(o0); ov.y = f2bf(o1);
          *reinterpret_cast<ushort2*>(Kb + (((size_t)(b * H + h) * NKV + kk) * DH + d0)) = ov;
        }
      } else {
        // V pass A: rotary+mask in coalesced K-path order, write back to Cs
#pragma unroll
        for (int i = 0; i < 16; ++i) {
          int p = i * 256 + t;
          int row = p >> 5, pc = p & 31, d0 = pc * 2;
          int grow = bm * 128 + row;
          float c0 = Cs[row][d0], c1 = Cs[row][d0 + 1];
          const float* f = rotc + (size_t)grow * DH + d0;
          float f0 = f[0], f1 = f[1], s0, s1, co0, co1;
          __sincosf(f0, &s0, &co0);
          __sincosf(f1, &s1, &co1);
          float mf = cmask[grow] ? 1.f : 0.f;
          Cs[row][d0]     = (c0 * co0 - c1 * s0) * mf;
          Cs[row][d0 + 1] = (c1 * co1 + c0 * s1) * mf;
        }
        __syncthreads();
        // V pass B: permute/pack from LDS only (no global loads, no sincos)
        int oc = t & 7;          // position octet
        int dd0 = t >> 3;        // 0..31
#pragma unroll
        for (int ch = 0; ch < 2; ++ch) {
          int ch64 = bm * 2 + ch;            // global 64-row chunk index
          int bb = ch64 >> 5, chunk = ch64 & 31;
          unsigned short* vbase = VTb + (((size_t)(bb * H + h) * 32 + chunk) * 64) * 64;
#pragma unroll
          for (int half = 0; half < 2; ++half) {
            int d = dd0 + half * 32;
            u32x4 pack;
#pragma unroll
            for (int j2 = 0; j2 < 4; ++j2) {
              unsigned int lohi[2];
#pragma unroll
              for (int e = 0; e < 2; ++e) {
                int p = oc * 8 + j2 * 2 + e;
                int pp = p & 31;
                int kv = (p >> 5) * 32 + ((pp & 1) ? ((pp >> 1) + 16) : (pp >> 1));
                lohi[e] = f2bf(Cs[ch * 64 + kv][d]);
              }
              pack[j2] = lohi[0] | (lohi[1] << 16);
            }
            *reinterpret_cast<u32x4*>(vbase + d * 64 + oc * 8) = pack;
          }
        }
      }
      __syncthreads();
    }
  } else {
    // ================= q path: 128x128 tiles =================
    int o2 = o - 1024;
    int swz = ((o2 & 7) << 5) | (o2 >> 3);
    int bn = swz & 3, bm = swz >> 2;     // bn: 128-col group (2 heads), bm: 128-row group
    gemm128_mainloop(xq_bf, WqT, As, Ws, bm * 128, bn * 128, acc);
#pragma unroll
    for (int hc = 0; hc < 2; ++hc) {
      if (wc == hc) {
#pragma unroll
        for (int m = 0; m < 4; ++m)
#pragma unroll
          for (int n = 0; n < 4; ++n)
#pragma unroll
            for (int r = 0; r < 4; ++r)
              Cs[wr * 64 + m * 16 + lg * 4 + r][n * 16 + l15] = acc[m][n][r];
      }
      __syncthreads();
      const int head = bn * 2 + hc;
#pragma unroll
      for (int i = 0; i < 16; ++i) {
        int p = i * 256 + t;
        int row = p >> 5, pc = p & 31, d0 = pc * 2;
        int grow = bm * 128 + row;           // b*NQ + q
        float c0 = Cs[row][d0], c1 = Cs[row][d0 + 1];
        const float* f = rotq + (size_t)grow * DH + d0;
        float f0 = f[0], f1 = f[1], s0, s1, co0, co1;
        __sincosf(f0, &s0, &co0);
        __sincosf(f1, &s1, &co1);
        float o0 = (c0 * co0 - c1 * s0) * SCALE_LOG2E;
        float o1 = (c1 * co1 + c0 * s1) * SCALE_LOG2E;
        ushort2 ov; ov.x = f2bf(o0); ov.y = f2bf(o1);
        int b = grow >> 10, qq = grow & 1023;
        *reinterpret_cast<ushort2*>(Qb + (((size_t)(b * H + head) * NQ + qq) * DH + d0)) = ov;
      }
      __syncthreads();
    }
  }
}

// ---------------- K4: flash attention -> hi/lo bf16 split output ----------------
// Swapped QK^T (mfma(K,Q) -> P^T): lane (lg,l15) holds P[q=w*16+l15]
// [kv=tt*16+lg*4+r] in registers. The V sigma image stores position pairs
// (2c,2c+1) <- kv (c,c+16) within each 32-block, so the PV A-fragment is
// assembled IN-LANE: pa.u[i] = cvt_pk(p[ks*2][i], p[ks*2+1][i]) — zero
// shuffles, zero LDS for P (8KB freed), no lgkmcnt drain.
// Double-buffered K/V, one barrier per tile. Mask pre-applied to K/V in
// proj; denominator corrected by n_masked.
__global__ __launch_bounds__(256) void attn_kernel(
    const unsigned short* __restrict__ Qb, const unsigned short* __restrict__ Kb,
    const unsigned short* __restrict__ VTb, const int* __restrict__ mask,
    const float* __restrict__ rotq,
    unsigned short* __restrict__ Ahb, unsigned short* __restrict__ Alb) {
  __shared__ unsigned short Ks[2 * 64 * 64];
  __shared__ unsigned short Vs[2 * 64 * 64];
  int ob = blockIdx.x;
  int swz = ((ob & 7) << 7) + (ob >> 3);
  int qb = swz & 15;
  int bh = swz >> 4;
  int b = bh >> 3, hh = bh & 7;
  int t = threadIdx.x, w = t >> 6, l = t & 63;
  int l15 = l & 15, lg = l >> 4;
  int c7 = l15 & 7;

  // n_masked: each wave redundantly popcounts the 8KB mask row (L2-hot, once)
  float nmasked;
  {
    const int* mrow = mask + b * NKV;
    float msum = 0.f;
#pragma unroll
    for (int i = 0; i < 8; ++i) {
      int4 m = *reinterpret_cast<const int4*>(mrow + l * 4 + i * 256);
      msum += (m.x ? 1.f : 0.f) + (m.y ? 1.f : 0.f) +
              (m.z ? 1.f : 0.f) + (m.w ? 1.f : 0.f);
    }
#pragma unroll
    for (int d = 1; d < 64; d <<= 1) msum += __shfl_xor(msum, d);
    nmasked = (float)NKV - msum;
  }

  const unsigned short* qrow = Qb + ((size_t)bh * NQ + qb * 64 + w * 16 + l15) * DH;
  bf16x8 qa0 = *reinterpret_cast<const bf16x8*>(qrow + lg * 8);
  bf16x8 qa1 = *reinterpret_cast<const bf16x8*>(qrow + 32 + lg * 8);

  float plsum = 0.f;
  f32x4 acc[4];
#pragma unroll
  for (int ct = 0; ct < 4; ++ct) acc[ct] = f32x4{0.f, 0.f, 0.f, 0.f};

  const int srow = t >> 2;
  const int sseg = (t & 3) * 16;
  const int sdst0 = srow * 64 + ((2 * (t & 3)) ^ (srow & 7)) * 8;
  const int frag = (lg ^ c7) * 8;
  const int kbase = l15 * 64 + frag;

  const unsigned short* gk = Kb + ((size_t)bh * NKV + srow) * DH + sseg;
  const unsigned short* gv = VTb + (((size_t)bh * 32) * 64 + srow) * 64 + sseg;

  // prologue: prefetch tile 0 into registers
  bf16x8 kr0 = *reinterpret_cast<const bf16x8*>(gk);
  bf16x8 kr1 = *reinterpret_cast<const bf16x8*>(gk + 8);
  bf16x8 vr0 = *reinterpret_cast<const bf16x8*>(gv);
  bf16x8 vr1 = *reinterpret_cast<const bf16x8*>(gv + 8);
  gk += 4096; gv += 4096;

#pragma unroll 2
  for (int ic = 0; ic < NKV / 64; ++ic) {
    const int bo_ = (ic & 1) << 12;   // double-buffer offset in shorts
    *reinterpret_cast<bf16x8*>(&Ks[bo_ + sdst0])       = kr0;
    *reinterpret_cast<bf16x8*>(&Ks[bo_ + (sdst0 ^ 8)]) = kr1;
    *reinterpret_cast<bf16x8*>(&Vs[bo_ + sdst0])       = vr0;
    *reinterpret_cast<bf16x8*>(&Vs[bo_ + (sdst0 ^ 8)]) = vr1;
    __syncthreads();
    if (ic + 1 < NKV / 64) {
      kr0 = *reinterpret_cast<const bf16x8*>(gk);
      kr1 = *reinterpret_cast<const bf16x8*>(gk + 8);
      vr0 = *reinterpret_cast<const bf16x8*>(gv);
      vr1 = *reinterpret_cast<const bf16x8*>(gv + 8);
      gk += 4096; gv += 4096;
    }
    // SWAPPED QK^T: mfma(K, Q) -> lane: q = l15, kv = tt*16 + lg*4 + r
    f32x4 s[4];
    __builtin_amdgcn_s_setprio(1);
#pragma unroll
    for (int tt = 0; tt < 4; ++tt) {
      f32x4 z = f32x4{0.f, 0.f, 0.f, 0.f};
      bf16x8 k0 = *reinterpret_cast<const bf16x8*>(&Ks[bo_ + tt * 1024 + kbase]);
      z = __builtin_amdgcn_mfma_f32_16x16x32_bf16(k0, qa0, z, 0, 0, 0);
      bf16x8 k1 = *reinterpret_cast<const bf16x8*>(&Ks[bo_ + tt * 1024 + (kbase ^ 32)]);
      z = __builtin_amdgcn_mfma_f32_16x16x32_bf16(k1, qa1, z, 0, 0, 0);
      s[tt] = z;
    }
    __builtin_amdgcn_s_setprio(0);
    // softmax: exp2; row (q) partial sum is lane-local
    float p[4][4];
#pragma unroll
    for (int tt = 0; tt < 4; ++tt)
#pragma unroll
      for (int r = 0; r < 4; ++r) {
        float e;
        asm("v_exp_f32 %0, %1" : "=v"(e) : "v"(s[tt][r]));
        p[tt][r] = e;
      }
    plsum += ((p[0][0] + p[0][1]) + (p[0][2] + p[0][3])) +
             ((p[1][0] + p[1][1]) + (p[1][2] + p[1][3])) +
             ((p[2][0] + p[2][1]) + (p[2][2] + p[2][3])) +
             ((p[3][0] + p[3][1]) + (p[3][2] + p[3][3]));
    // PV: A-fragment assembled IN-LANE. V position perm within each 32-block
    // is (2c,2c+1) <- kv (c,c+16); element e of the ks-fragment needs
    // kv = ks*32 + 16*(e&1) + lg*4 + (e>>1) = p[ks*2+(e&1)][e>>1]. So:
    __builtin_amdgcn_s_setprio(1);
#pragma unroll
    for (int ks = 0; ks < 2; ++ks) {
      union { u32x4 u; bf16x8 b; } pa;
#pragma unroll
      for (int i = 0; i < 4; ++i)
        asm("v_cvt_pk_bf16_f32 %0, %1, %2"
            : "=v"(pa.u[i]) : "v"(p[ks * 2][i]), "v"(p[ks * 2 + 1][i]));
#pragma unroll
      for (int ct = 0; ct < 4; ++ct) {
        bf16x8 vb = *reinterpret_cast<const bf16x8*>(
            &Vs[bo_ + ct * 1024 + (kbase ^ (ks ? 32 : 0))]);
        acc[ct] = __builtin_amdgcn_mfma_f32_16x16x32_bf16(pa.b, vb, acc[ct], 0, 0, 0);
      }
    }
    __builtin_amdgcn_s_setprio(0);
  }
  // reduce plsum across the 4 lane-groups (same l15 = same q)
  plsum += __shfl_xor(plsum, 16);
  plsum += __shfl_xor(plsum, 32);
  float inv[4];
#pragma unroll
  for (int r = 0; r < 4; ++r)
    inv[r] = 1.0f / (__shfl(plsum, lg * 4 + r) - nmasked);

  int q0 = qb * 64 + w * 16 + lg * 4;
#pragma unroll
  for (int r = 0; r < 4; ++r) {
    int grow = b * NQ + q0 + r;
    const float* frow = rotq + (size_t)grow * DH;
    size_t obase = (size_t)grow * INNER + hh * DH;
#pragma unroll
    for (int ct = 0; ct < 4; ++ct) {
      int d = ct * 16 + l15;
      float x = acc[ct][r] * inv[r];
      float nb = __shfl_xor(x, 1);
      float f = frow[d];
      float sn, cs;
      __sincosf(f, &sn, &cs);
      float ov = (d & 1) ? (x * cs - nb * sn) : (x * cs + nb * sn);
      unsigned short hb = f2bf(ov);
      Ahb[obase + d] = hb;
      Alb[obase + d] = f2bf(ov - bf2f(hb));
    }
  }
}

// ---------------- K_D: final GEMM, bf16 hi/lo split (3-term), 128x64 tiles ----------------
// out = Ah*Wh + Al*Wh + Ah*Wl + bias   (Al*Wl dropped, ~2^-18 relative)
// 512 blocks -> 2 blocks/CU. Tile grid: 64 row-groups x 8 col-groups.
__global__ __launch_bounds__(256) void final_gemm(
    const unsigned short* __restrict__ Ah, const unsigned short* __restrict__ Al,
    const unsigned short* __restrict__ Wh, const unsigned short* __restrict__ Wl,
    const float* __restrict__ bo, float* __restrict__ out) {
  __shared__ __align__(16) char smem[49152];
  unsigned short* AhS = (unsigned short*)smem;            // 128x64
  unsigned short* AlS = (unsigned short*)(smem + 16384);  // 128x64
  unsigned short* WhS = (unsigned short*)(smem + 32768);  //  64x64
  unsigned short* WlS = (unsigned short*)(smem + 40960);  //  64x64
  int o = blockIdx.x;                    // 512 blocks
  int swz = ((o & 7) << 6) | (o >> 3);
  int bn = swz & 7, bm = swz >> 3;       // bn: 64-col group (0..7), bm: 128-row group (0..63)
  const int t = threadIdx.x;
  const int w = t >> 6, l = t & 63;
  const int l15 = l & 15, lg = l >> 4, c7 = l15 & 7;
  const int wr = w >> 1, wc = w & 1;
  const int lrow = l >> 3;
  const int lchunk = (l & 7) ^ lrow;
  const int frag = (lg ^ c7) * 8;
  const unsigned short* Agh = Ah + (size_t)bm * 128 * 512;
  const unsigned short* Agl = Al + (size_t)bm * 128 * 512;
  const unsigned short* Wgh = Wh + (size_t)bn * 64 * 512;
  const unsigned short* Wgl = Wl + (size_t)bn * 64 * 512;
  f32x4 acc[4][2];
#pragma unroll
  for (int m = 0; m < 4; ++m)
#pragma unroll
    for (int n = 0; n < 2; ++n) acc[m][n] = f32x4{0.f, 0.f, 0.f, 0.f};
  for (int kb = 0; kb < 512; kb += 64) {
#pragma unroll
    for (int i = 0; i < 4; ++i) {
      const int seg = w * 4 + i;                       // 16 segs of 8 rows (A: 128 rows)
      const size_t goff = (size_t)(seg * 8 + lrow) * 512 + kb + lchunk * 8;
      gl_lds16(Agh + goff, AhS + seg * 512);
      gl_lds16(Agl + goff, AlS + seg * 512);
    }
#pragma unroll
    for (int i = 0; i < 2; ++i) {
      const int seg = w * 2 + i;                       // 8 segs of 8 rows (W: 64 rows)
      const size_t goff = (size_t)(seg * 8 + lrow) * 512 + kb + lchunk * 8;
      gl_lds16(Wgh + goff, WhS + seg * 512);
      gl_lds16(Wgl + goff, WlS + seg * 512);
    }
    __syncthreads();
#pragma unroll
    for (int ks = 0; ks < 2; ++ks) {
      const int xo = ks ? 32 : 0;
      bf16x8 ah[4], al[4], wh[2], wl[2];
#pragma unroll
      for (int m = 0; m < 4; ++m) {
        const int off = (wr * 64 + m * 16 + l15) * 64 + (frag ^ xo);
        ah[m] = *reinterpret_cast<const bf16x8*>(&AhS[off]);
        al[m] = *reinterpret_cast<const bf16x8*>(&AlS[off]);
      }
#pragma unroll
      for (int n = 0; n < 2; ++n) {
        const int off = (wc * 32 + n * 16 + l15) * 64 + (frag ^ xo);
        wh[n] = *reinterpret_cast<const bf16x8*>(&WhS[off]);
        wl[n] = *reinterpret_cast<const bf16x8*>(&WlS[off]);
      }
#pragma unroll
      for (int m = 0; m < 4; ++m)
#pragma unroll
        for (int n = 0; n < 2; ++n) {
          acc[m][n] = __builtin_amdgcn_mfma_f32_16x16x32_bf16(ah[m], wh[n], acc[m][n], 0, 0, 0);
          acc[m][n] = __builtin_amdgcn_mfma_f32_16x16x32_bf16(al[m], wh[n], acc[m][n], 0, 0, 0);
          acc[m][n] = __builtin_amdgcn_mfma_f32_16x16x32_bf16(ah[m], wl[n], acc[m][n], 0, 0, 0);
        }
    }
    __syncthreads();
  }
  const int row0 = bm * 128 + wr * 64;
  const int col0 = bn * 64 + wc * 32;
#pragma unroll
  for (int m = 0; m < 4; ++m)
#pragma unroll
    for (int n = 0; n < 2; ++n) {
      int col = col0 + n * 16 + l15;
      float bv = bo[col];
#pragma unroll
      for (int r = 0; r < 4; ++r)
        out[(size_t)(row0 + m * 16 + lg * 4 + r) * 512 + col] = acc[m][n][r] + bv;
    }
}

extern "C" void kernel_launch(void* const* d_in, const int* in_sizes, int n_in,
                              void* d_out, int out_size, void* d_ws, size_t ws_size,
                              hipStream_t stream) {
  const float* x_query   = (const float*)d_in[0];
  const float* x_context = (const float*)d_in[1];
  const float* rot_q     = (const float*)d_in[2];
  const float* rot_c     = (const float*)d_in[3];
  const int*   cmask     = (const int*)d_in[4];
  const float* ln_q_g    = (const float*)d_in[5];
  const float* ln_q_b    = (const float*)d_in[6];
  const float* ln_c_g    = (const float*)d_in[7];
  const float* ln_c_b    = (const float*)d_in[8];
  const float* Wq        = (const float*)d_in[9];
  const float* Wkv       = (const float*)d_in[10];
  const float* Wo        = (const float*)d_in[11];
  const float* bo        = (const float*)d_in[12];
  float* out = (float*)d_out;

  char* ws = (char*)d_ws;
  unsigned short* xq_bf = (unsigned short*)(ws + 0);          // 8 MB
  unsigned short* xc_bf = (unsigned short*)(ws + 8388608);    // 16 MB
  unsigned short* Ahb   = (unsigned short*)(ws + 0);          // 8 MB (after projections)
  unsigned short* Alb   = (unsigned short*)(ws + 8388608);    // 8 MB (after proj)
  unsigned short* WqT   = (unsigned short*)(ws + 25165824);   // 0.5 MB
  unsigned short* WkvT  = (unsigned short*)(ws + 25690112);   // 1 MB
  unsigned short* Qb    = (unsigned short*)(ws + 26738688);   // 8 MB
  unsigned short* Kb    = (unsigned short*)(ws + 35127296);   // 16 MB
  unsigned short* VTb   = (unsigned short*)(ws + 51904512);   // 16 MB
  unsigned short* WohT  = (unsigned short*)(ws + 68681728);   // 0.5 MB
  unsigned short* WolT  = (unsigned short*)(ws + 69206016);   // 0.5 MB

  prep_ln<<<dim3(2304), dim3(256), 0, stream>>>(
      Wq, Wkv, Wo, WqT, WkvT, WohT, WolT,
      x_query, x_context, ln_q_g, ln_q_b, ln_c_g, ln_c_b, xq_bf, xc_bf);
  proj_fused<<<dim3(1280), dim3(256), 0, stream>>>(
      xq_bf, xc_bf, WqT, WkvT, rot_q, rot_c, cmask, Qb, Kb, VTb);
  attn_kernel<<<dim3(1024), dim3(256), 0, stream>>>(Qb, Kb, VTb, cmask, rot_q, Ahb, Alb);
  final_gemm<<<dim3(512), dim3(256), 0, stream>>>(Ahb, Alb, WohT, WolT, bo, out);
}

// Round 14
// 127.045 us; speedup vs baseline: 1.2198x; 1.0644x over previous
//
#include <hip/hip_runtime.h>
#include <hip/hip_bf16.h>
#include <math.h>

#define BB 8
#define NQ 1024
#define NKV 2048
#define DIM 512
#define H 8
#define DH 64
#define INNER 512
// 0.125 * log2(e): folded into Q so QK^T scores feed v_exp_f32 (2^x) directly
#define SCALE_LOG2E 0.18033688011112042f

typedef __bf16 bf16x8 __attribute__((ext_vector_type(8)));
typedef float f32x4 __attribute__((ext_vector_type(4)));
typedef unsigned int u32x4 __attribute__((ext_vector_type(4)));

__device__ __forceinline__ unsigned short f2bf(float f) {
  union { float f; unsigned int u; } v; v.f = f;
  unsigned int r = v.u + 0x7fffu + ((v.u >> 16) & 1u);
  return (unsigned short)(r >> 16);
}
__device__ __forceinline__ float bf2f(unsigned short h) {
  union { unsigned int u; float f; } v; v.u = ((unsigned int)h) << 16;
  return v.f;
}

// async global->LDS, 16B per lane. LDS dest = wave-uniform base + lane*16 (linear).
__device__ __forceinline__ void gl_lds16(const unsigned short* g, unsigned short* l) {
  __builtin_amdgcn_global_load_lds(
      (const __attribute__((address_space(1))) unsigned int*)g,
      (__attribute__((address_space(3))) unsigned int*)l, 16, 0, 0);
}

// ---------------- K_A: fused LN (blocks 0..2047, 12 rows each) +
//                  weight cast/transpose (blocks 2048..2303) ----------------
// LN path: ONE WAVE PER ROW (64 lanes x 8 floats = DIM), float4x2 loads,
// pure-shuffle reduction, ZERO barriers (old version: 24 barriers/block),
// b128 packed store. Each wave independently processes 3 rows.
__global__ __launch_bounds__(256) void prep_ln(
    const float* __restrict__ Wq, const float* __restrict__ Wkv,
    const float* __restrict__ Wo,
    unsigned short* __restrict__ WqT, unsigned short* __restrict__ WkvT,
    unsigned short* __restrict__ WohT, unsigned short* __restrict__ WolT,
    const float* __restrict__ xq, const float* __restrict__ xc,
    const float* __restrict__ gq, const float* __restrict__ bq,
    const float* __restrict__ gc, const float* __restrict__ bc,
    unsigned short* __restrict__ xq_bf, unsigned short* __restrict__ xc_bf) {
  __shared__ float T[64][65];
  int blk = blockIdx.x;
  int t = threadIdx.x;
  if (blk < 2048) {
    // ---- LayerNorm path: 12 rows per block, 3 per wave ----
    int wv = t >> 6, lane = t & 63;
#pragma unroll
    for (int rr = 0; rr < 3; ++rr) {
      int row = blk * 12 + wv * 3 + rr;     // 0..24575
      const float* x; const float* g; const float* bbv; unsigned short* outp;
      if (row < BB * NQ) {
        x = xq + (size_t)row * DIM; g = gq; bbv = bq; outp = xq_bf + (size_t)row * DIM;
      } else {
        int r2 = row - BB * NQ;
        x = xc + (size_t)r2 * DIM; g = gc; bbv = bc; outp = xc_bf + (size_t)r2 * DIM;
      }
      float4 v0 = *reinterpret_cast<const float4*>(x + lane * 8);
      float4 v1 = *reinterpret_cast<const float4*>(x + lane * 8 + 4);
      float s  = ((v0.x + v0.y) + (v0.z + v0.w)) + ((v1.x + v1.y) + (v1.z + v1.w));
      float ss = ((v0.x * v0.x + v0.y * v0.y) + (v0.z * v0.z + v0.w * v0.w)) +
                 ((v1.x * v1.x + v1.y * v1.y) + (v1.z * v1.z + v1.w * v1.w));
#pragma unroll
      for (int d = 1; d < 64; d <<= 1) { s += __shfl_xor(s, d); ss += __shfl_xor(ss, d); }
      float mu = s * (1.0f / DIM);
      float var = ss * (1.0f / DIM) - mu * mu;
      float rs = rsqrtf(var + 1e-5f);
      float4 g0 = *reinterpret_cast<const float4*>(g + lane * 8);
      float4 g1 = *reinterpret_cast<const float4*>(g + lane * 8 + 4);
      float4 b0 = *reinterpret_cast<const float4*>(bbv + lane * 8);
      float4 b1 = *reinterpret_cast<const float4*>(bbv + lane * 8 + 4);
      float y0 = (v0.x - mu) * rs * g0.x + b0.x;
      float y1 = (v0.y - mu) * rs * g0.y + b0.y;
      float y2 = (v0.z - mu) * rs * g0.z + b0.z;
      float y3 = (v0.w - mu) * rs * g0.w + b0.w;
      float y4 = (v1.x - mu) * rs * g1.x + b1.x;
      float y5 = (v1.y - mu) * rs * g1.y + b1.y;
      float y6 = (v1.z - mu) * rs * g1.z + b1.z;
      float y7 = (v1.w - mu) * rs * g1.w + b1.w;
      u32x4 o;
      o[0] = (unsigned int)f2bf(y0) | ((unsigned int)f2bf(y1) << 16);
      o[1] = (unsigned int)f2bf(y2) | ((unsigned int)f2bf(y3) << 16);
      o[2] = (unsigned int)f2bf(y4) | ((unsigned int)f2bf(y5) << 16);
      o[3] = (unsigned int)f2bf(y6) | ((unsigned int)f2bf(y7) << 16);
      *reinterpret_cast<u32x4*>(outp + lane * 8) = o;
    }
  } else {
    // ---- weight prep path ----
    int blk2 = blk - 2048;
    const float* src; int Wd, ti, tj, mode;
    unsigned short* dst = nullptr;
    if (blk2 < 64) { src = Wq;  dst = WqT;  Wd = 512;  ti = blk2 >> 3; tj = blk2 & 7; mode = 0; }
    else if (blk2 < 192) { int b2 = blk2 - 64; src = Wkv; dst = WkvT; Wd = 1024; ti = b2 >> 4; tj = b2 & 15; mode = 0; }
    else { int b2 = blk2 - 192; src = Wo; Wd = 512; ti = b2 >> 3; tj = b2 & 7; mode = 1; }
#pragma unroll
    for (int i = 0; i < 16; ++i) {
      int idx = i * 256 + t;
      int r = idx >> 6, c = idx & 63;
      T[r][c] = src[(size_t)(ti * 64 + r) * Wd + tj * 64 + c];
    }
    __syncthreads();
#pragma unroll
    for (int i = 0; i < 16; ++i) {
      int idx = i * 256 + t;
      int n = idx >> 6, k = idx & 63;
      float v = T[k][n];
      size_t off = (size_t)(tj * 64 + n) * 512 + ti * 64 + k;
      if (mode == 0) {
        dst[off] = f2bf(v);
      } else {
        unsigned short hb = f2bf(v);
        WohT[off] = hb;
        WolT[off] = f2bf(v - bf2f(hb));
      }
    }
  }
}

// ---------------- 128x128 MFMA mainloop (m97 structure) ----------------
// 4 waves in 2x2, each owns a 64x64 quadrant (acc[4][4] f32x4).
// Staging: global_load_lds width=16, linear LDS dest, PRE-SWIZZLED global
// source (chunk ^= row&7) so the LDS image matches the conflict-free
// XOR-swizzled ds_read_b128 pattern. BK=64, 8 K-steps, 2 barriers each.
// NOTE (R11 lesson): 2-phase double-buffering (64KB LDS) halves residency
// to 2 blocks/CU and REGRESSES (54->78us, occ 17->10%) — cross-block TLP
// is the dominant latency hider here; keep 32KB / 4 blocks/CU.
__device__ __forceinline__ void gemm128_mainloop(
    const unsigned short* __restrict__ A, const unsigned short* __restrict__ WT,
    unsigned short* As, unsigned short* Ws,
    int rowBase, int colBase, f32x4 acc[4][4]) {
  const int t = threadIdx.x;
  const int w = t >> 6, l = t & 63;
  const int l15 = l & 15, lg = l >> 4, c7 = l15 & 7;
  const int wr = w >> 1, wc = w & 1;
  const int lrow = l >> 3;                 // 0..7 within a 1KB segment
  const int lchunk = (l & 7) ^ lrow;       // pre-swizzled global 16B chunk
  const int frag = (lg ^ c7) * 8;
  const unsigned short* Ag = A + (size_t)rowBase * 512;
  const unsigned short* Wg = WT + (size_t)colBase * 512;
#pragma unroll
  for (int m = 0; m < 4; ++m)
#pragma unroll
    for (int n = 0; n < 4; ++n) acc[m][n] = f32x4{0.f, 0.f, 0.f, 0.f};
  for (int kb = 0; kb < 512; kb += 64) {
#pragma unroll
    for (int i = 0; i < 4; ++i) {
      const int seg = w * 4 + i;                       // 16 segs of 8 rows
      const size_t goff = (size_t)(seg * 8 + lrow) * 512 + kb + lchunk * 8;
      gl_lds16(Ag + goff, As + seg * 512);
      gl_lds16(Wg + goff, Ws + seg * 512);
    }
    __syncthreads();   // drains vmcnt -> staged data visible
#pragma unroll
    for (int ks = 0; ks < 2; ++ks) {
      const int xo = ks ? 32 : 0;
      bf16x8 af[4], bf_[4];
#pragma unroll
      for (int m = 0; m < 4; ++m)
        af[m] = *reinterpret_cast<const bf16x8*>(
            &As[(wr * 64 + m * 16 + l15) * 64 + (frag ^ xo)]);
#pragma unroll
      for (int n = 0; n < 4; ++n)
        bf_[n] = *reinterpret_cast<const bf16x8*>(
            &Ws[(wc * 64 + n * 16 + l15) * 64 + (frag ^ xo)]);
#pragma unroll
      for (int m = 0; m < 4; ++m)
#pragma unroll
        for (int n = 0; n < 4; ++n)
          acc[m][n] = __builtin_amdgcn_mfma_f32_16x16x32_bf16(af[m], bf_[n], acc[m][n], 0, 0, 0);
    }
    __syncthreads();
  }
}

// ---------------- K_B: fused projections ----------------
// blocks 0..1023: kv 128x128 tiles (K masked+rotary, V sigma image masked)
// blocks 1024..1279: q 128x128 tiles (rotary + scale*log2e)
// V epilogue is TWO-PASS: pass A applies rotary+mask in coalesced K-path
// order writing back into Cs; pass B permutes/packs from LDS only.
__global__ __launch_bounds__(256) void proj_fused(
    const unsigned short* __restrict__ xq_bf, const unsigned short* __restrict__ xc_bf,
    const unsigned short* __restrict__ WqT, const unsigned short* __restrict__ WkvT,
    const float* __restrict__ rotq, const float* __restrict__ rotc,
    const int* __restrict__ cmask,
    unsigned short* __restrict__ Qb, unsigned short* __restrict__ Kb,
    unsigned short* __restrict__ VTb) {
  __shared__ __align__(16) char smem[128 * 66 * 4];   // staging (32KB) U Cs half (33KB)
  unsigned short* As = (unsigned short*)smem;
  unsigned short* Ws = (unsigned short*)(smem + 16384);
  float (*Cs)[66] = (float(*)[66])smem;
  const int t = threadIdx.x;
  const int w = t >> 6, l = t & 63;
  const int l15 = l & 15, lg = l >> 4;
  const int wr = w >> 1, wc = w & 1;
  f32x4 acc[4][4];
  int o = blockIdx.x;
  if (o < 1024) {
    // ================= kv path =================
    int swz = ((o & 7) << 7) | (o >> 3);
    int bn = swz & 7, bm = swz >> 3;     // bn: 128-col group (0..7), bm: 128-row group
    gemm128_mainloop(xc_bf, WkvT, As, Ws, bm * 128, bn * 128, acc);
#pragma unroll
    for (int hc = 0; hc < 2; ++hc) {
      if (wc == hc) {
#pragma unroll
        for (int m = 0; m < 4; ++m)
#pragma unroll
          for (int n = 0; n < 4; ++n)
#pragma unroll
            for (int r = 0; r < 4; ++r)
              Cs[wr * 64 + m * 16 + lg * 4 + r][n * 16 + l15] = acc[m][n][r];
      }
      __syncthreads();
      const int g = bn * 2 + hc;           // 64-col group 0..15
      const int h = g & 7;
      if (g < 8) {
        // K path: rotary+mask, coalesced, direct store
#pragma unroll
        for (int i = 0; i < 16; ++i) {
          int p = i * 256 + t;
          int row = p >> 5, pc = p & 31, d0 = pc * 2;
          int grow = bm * 128 + row;         // b*NKV + kv
          float c0 = Cs[row][d0], c1 = Cs[row][d0 + 1];
          const float* f = rotc + (size_t)grow * DH + d0;
          float f0 = f[0], f1 = f[1], s0, s1, co0, co1;
          __sincosf(f0, &s0, &co0);
          __sincosf(f1, &s1, &co1);
          float mf = cmask[grow] ? 1.f : 0.f;
          float o0 = (c0 * co0 - c1 * s0) * mf;
          float o1 = (c1 * co1 + c0 * s1) * mf;
          int b = grow >> 11, kk = grow & 2047;
          ushort2 ov; ov.x = f2bf(o0); ov.y = f2bf(o1);
          *reinterpret_cast<ushort2*>(Kb + (((size_t)(b * H + h) * NKV + kk) * DH + d0)) = ov;
        }
      } else {
        // V pass A: rotary+mask in coalesced K-path order, write back to Cs
#pragma unroll
        for (int i = 0; i < 16; ++i) {
          int p = i * 256 + t;
          int row = p >> 5, pc = p & 31, d0 = pc * 2;
          int grow = bm * 128 + row;
          float c0 = Cs[row][d0], c1 = Cs[row][d0 + 1];
          const float* f = rotc + (size_t)grow * DH + d0;
          float f0 = f[0], f1 = f[1], s0, s1, co0, co1;
          __sincosf(f0, &s0, &co0);
          __sincosf(f1, &s1, &co1);
          float mf = cmask[grow] ? 1.f : 0.f;
          Cs[row][d0]     = (c0 * co0 - c1 * s0) * mf;
          Cs[row][d0 + 1] = (c1 * co1 + c0 * s1) * mf;
        }
        __syncthreads();
        // V pass B: permute/pack from LDS only (no global loads, no sincos)
        int oc = t & 7;          // position octet
        int dd0 = t >> 3;        // 0..31
#pragma unroll
        for (int ch = 0; ch < 2; ++ch) {
          int ch64 = bm * 2 + ch;            // global 64-row chunk index
          int bb = ch64 >> 5, chunk = ch64 & 31;
          unsigned short* vbase = VTb + (((size_t)(bb * H + h) * 32 + chunk) * 64) * 64;
#pragma unroll
          for (int half = 0; half < 2; ++half) {
            int d = dd0 + half * 32;
            u32x4 pack;
#pragma unroll
            for (int j2 = 0; j2 < 4; ++j2) {
              unsigned int lohi[2];
#pragma unroll
              for (int e = 0; e < 2; ++e) {
                int p = oc * 8 + j2 * 2 + e;
                int pp = p & 31;
                int kv = (p >> 5) * 32 + ((pp & 1) ? ((pp >> 1) + 16) : (pp >> 1));
                lohi[e] = f2bf(Cs[ch * 64 + kv][d]);
              }
              pack[j2] = lohi[0] | (lohi[1] << 16);
            }
            *reinterpret_cast<u32x4*>(vbase + d * 64 + oc * 8) = pack;
          }
        }
      }
      __syncthreads();
    }
  } else {
    // ================= q path: 128x128 tiles =================
    int o2 = o - 1024;
    int swz = ((o2 & 7) << 5) | (o2 >> 3);
    int bn = swz & 3, bm = swz >> 2;     // bn: 128-col group (2 heads), bm: 128-row group
    gemm128_mainloop(xq_bf, WqT, As, Ws, bm * 128, bn * 128, acc);
#pragma unroll
    for (int hc = 0; hc < 2; ++hc) {
      if (wc == hc) {
#pragma unroll
        for (int m = 0; m < 4; ++m)
#pragma unroll
          for (int n = 0; n < 4; ++n)
#pragma unroll
            for (int r = 0; r < 4; ++r)
              Cs[wr * 64 + m * 16 + lg * 4 + r][n * 16 + l15] = acc[m][n][r];
      }
      __syncthreads();
      const int head = bn * 2 + hc;
#pragma unroll
      for (int i = 0; i < 16; ++i) {
        int p = i * 256 + t;
        int row = p >> 5, pc = p & 31, d0 = pc * 2;
        int grow = bm * 128 + row;           // b*NQ + q
        float c0 = Cs[row][d0], c1 = Cs[row][d0 + 1];
        const float* f = rotq + (size_t)grow * DH + d0;
        float f0 = f[0], f1 = f[1], s0, s1, co0, co1;
        __sincosf(f0, &s0, &co0);
        __sincosf(f1, &s1, &co1);
        float o0 = (c0 * co0 - c1 * s0) * SCALE_LOG2E;
        float o1 = (c1 * co1 + c0 * s1) * SCALE_LOG2E;
        ushort2 ov; ov.x = f2bf(o0); ov.y = f2bf(o1);
        int b = grow >> 10, qq = grow & 1023;
        *reinterpret_cast<ushort2*>(Qb + (((size_t)(b * H + head) * NQ + qq) * DH + d0)) = ov;
      }
      __syncthreads();
    }
  }
}

// ---------------- K4: flash attention -> hi/lo bf16 split output ----------------
// Swapped QK^T (mfma(K,Q) -> P^T): lane (lg,l15) holds P[q=w*16+l15]
// [kv=tt*16+lg*4+r] in registers. The V sigma image stores position pairs
// (2c,2c+1) <- kv (c,c+16) within each 32-block, so the PV A-fragment is
// assembled IN-LANE: pa.u[i] = cvt_pk(p[ks*2][i], p[ks*2+1][i]) — zero
// shuffles, zero LDS for P (8KB freed), no lgkmcnt drain.
// Double-buffered K/V, one barrier per tile. Mask pre-applied to K/V in
// proj; denominator corrected by n_masked.
__global__ __launch_bounds__(256) void attn_kernel(
    const unsigned short* __restrict__ Qb, const unsigned short* __restrict__ Kb,
    const unsigned short* __restrict__ VTb, const int* __restrict__ mask,
    const float* __restrict__ rotq,
    unsigned short* __restrict__ Ahb, unsigned short* __restrict__ Alb) {
  __shared__ unsigned short Ks[2 * 64 * 64];
  __shared__ unsigned short Vs[2 * 64 * 64];
  int ob = blockIdx.x;
  int swz = ((ob & 7) << 7) + (ob >> 3);
  int qb = swz & 15;
  int bh = swz >> 4;
  int b = bh >> 3, hh = bh & 7;
  int t = threadIdx.x, w = t >> 6, l = t & 63;
  int l15 = l & 15, lg = l >> 4;
  int c7 = l15 & 7;

  // n_masked: each wave redundantly popcounts the 8KB mask row (L2-hot, once)
  float nmasked;
  {
    const int* mrow = mask + b * NKV;
    float msum = 0.f;
#pragma unroll
    for (int i = 0; i < 8; ++i) {
      int4 m = *reinterpret_cast<const int4*>(mrow + l * 4 + i * 256);
      msum += (m.x ? 1.f : 0.f) + (m.y ? 1.f : 0.f) +
              (m.z ? 1.f : 0.f) + (m.w ? 1.f : 0.f);
    }
#pragma unroll
    for (int d = 1; d < 64; d <<= 1) msum += __shfl_xor(msum, d);
    nmasked = (float)NKV - msum;
  }

  const unsigned short* qrow = Qb + ((size_t)bh * NQ + qb * 64 + w * 16 + l15) * DH;
  bf16x8 qa0 = *reinterpret_cast<const bf16x8*>(qrow + lg * 8);
  bf16x8 qa1 = *reinterpret_cast<const bf16x8*>(qrow + 32 + lg * 8);

  float plsum = 0.f;
  f32x4 acc[4];
#pragma unroll
  for (int ct = 0; ct < 4; ++ct) acc[ct] = f32x4{0.f, 0.f, 0.f, 0.f};

  const int srow = t >> 2;
  const int sseg = (t & 3) * 16;
  const int sdst0 = srow * 64 + ((2 * (t & 3)) ^ (srow & 7)) * 8;
  const int frag = (lg ^ c7) * 8;
  const int kbase = l15 * 64 + frag;

  const unsigned short* gk = Kb + ((size_t)bh * NKV + srow) * DH + sseg;
  const unsigned short* gv = VTb + (((size_t)bh * 32) * 64 + srow) * 64 + sseg;

  // prologue: prefetch tile 0 into registers
  bf16x8 kr0 = *reinterpret_cast<const bf16x8*>(gk);
  bf16x8 kr1 = *reinterpret_cast<const bf16x8*>(gk + 8);
  bf16x8 vr0 = *reinterpret_cast<const bf16x8*>(gv);
  bf16x8 vr1 = *reinterpret_cast<const bf16x8*>(gv + 8);
  gk += 4096; gv += 4096;

#pragma unroll 2
  for (int ic = 0; ic < NKV / 64; ++ic) {
    const int bo_ = (ic & 1) << 12;   // double-buffer offset in shorts
    *reinterpret_cast<bf16x8*>(&Ks[bo_ + sdst0])       = kr0;
    *reinterpret_cast<bf16x8*>(&Ks[bo_ + (sdst0 ^ 8)]) = kr1;
    *reinterpret_cast<bf16x8*>(&Vs[bo_ + sdst0])       = vr0;
    *reinterpret_cast<bf16x8*>(&Vs[bo_ + (sdst0 ^ 8)]) = vr1;
    __syncthreads();
    if (ic + 1 < NKV / 64) {
      kr0 = *reinterpret_cast<const bf16x8*>(gk);
      kr1 = *reinterpret_cast<const bf16x8*>(gk + 8);
      vr0 = *reinterpret_cast<const bf16x8*>(gv);
      vr1 = *reinterpret_cast<const bf16x8*>(gv + 8);
      gk += 4096; gv += 4096;
    }
    // SWAPPED QK^T: mfma(K, Q) -> lane: q = l15, kv = tt*16 + lg*4 + r
    f32x4 s[4];
    __builtin_amdgcn_s_setprio(1);
#pragma unroll
    for (int tt = 0; tt < 4; ++tt) {
      f32x4 z = f32x4{0.f, 0.f, 0.f, 0.f};
      bf16x8 k0 = *reinterpret_cast<const bf16x8*>(&Ks[bo_ + tt * 1024 + kbase]);
      z = __builtin_amdgcn_mfma_f32_16x16x32_bf16(k0, qa0, z, 0, 0, 0);
      bf16x8 k1 = *reinterpret_cast<const bf16x8*>(&Ks[bo_ + tt * 1024 + (kbase ^ 32)]);
      z = __builtin_amdgcn_mfma_f32_16x16x32_bf16(k1, qa1, z, 0, 0, 0);
      s[tt] = z;
    }
    __builtin_amdgcn_s_setprio(0);
    // softmax: exp2; row (q) partial sum is lane-local
    float p[4][4];
#pragma unroll
    for (int tt = 0; tt < 4; ++tt)
#pragma unroll
      for (int r = 0; r < 4; ++r) {
        float e;
        asm("v_exp_f32 %0, %1" : "=v"(e) : "v"(s[tt][r]));
        p[tt][r] = e;
      }
    plsum += ((p[0][0] + p[0][1]) + (p[0][2] + p[0][3])) +
             ((p[1][0] + p[1][1]) + (p[1][2] + p[1][3])) +
             ((p[2][0] + p[2][1]) + (p[2][2] + p[2][3])) +
             ((p[3][0] + p[3][1]) + (p[3][2] + p[3][3]));
    // PV: A-fragment assembled IN-LANE. V position perm within each 32-block
    // is (2c,2c+1) <- kv (c,c+16); element e of the ks-fragment needs
    // kv = ks*32 + 16*(e&1) + lg*4 + (e>>1) = p[ks*2+(e&1)][e>>1]. So:
    __builtin_amdgcn_s_setprio(1);
#pragma unroll
    for (int ks = 0; ks < 2; ++ks) {
      union { u32x4 u; bf16x8 b; } pa;
#pragma unroll
      for (int i = 0; i < 4; ++i)
        asm("v_cvt_pk_bf16_f32 %0, %1, %2"
            : "=v"(pa.u[i]) : "v"(p[ks * 2][i]), "v"(p[ks * 2 + 1][i]));
#pragma unroll
      for (int ct = 0; ct < 4; ++ct) {
        bf16x8 vb = *reinterpret_cast<const bf16x8*>(
            &Vs[bo_ + ct * 1024 + (kbase ^ (ks ? 32 : 0))]);
        acc[ct] = __builtin_amdgcn_mfma_f32_16x16x32_bf16(pa.b, vb, acc[ct], 0, 0, 0);
      }
    }
    __builtin_amdgcn_s_setprio(0);
  }
  // reduce plsum across the 4 lane-groups (same l15 = same q)
  plsum += __shfl_xor(plsum, 16);
  plsum += __shfl_xor(plsum, 32);
  float inv[4];
#pragma unroll
  for (int r = 0; r < 4; ++r)
    inv[r] = 1.0f / (__shfl(plsum, lg * 4 + r) - nmasked);

  int q0 = qb * 64 + w * 16 + lg * 4;
#pragma unroll
  for (int r = 0; r < 4; ++r) {
    int grow = b * NQ + q0 + r;
    const float* frow = rotq + (size_t)grow * DH;
    size_t obase = (size_t)grow * INNER + hh * DH;
#pragma unroll
    for (int ct = 0; ct < 4; ++ct) {
      int d = ct * 16 + l15;
      float x = acc[ct][r] * inv[r];
      float nb = __shfl_xor(x, 1);
      float f = frow[d];
      float sn, cs;
      __sincosf(f, &sn, &cs);
      float ov = (d & 1) ? (x * cs - nb * sn) : (x * cs + nb * sn);
      unsigned short hb = f2bf(ov);
      Ahb[obase + d] = hb;
      Alb[obase + d] = f2bf(ov - bf2f(hb));
    }
  }
}

// ---------------- K_D: final GEMM, bf16 hi/lo split (3-term), 128x64 tiles ----------------
// out = Ah*Wh + Al*Wh + Ah*Wl + bias   (Al*Wl dropped, ~2^-18 relative)
// 512 blocks -> 2 blocks/CU. Tile grid: 64 row-groups x 8 col-groups.
__global__ __launch_bounds__(256) void final_gemm(
    const unsigned short* __restrict__ Ah, const unsigned short* __restrict__ Al,
    const unsigned short* __restrict__ Wh, const unsigned short* __restrict__ Wl,
    const float* __restrict__ bo, float* __restrict__ out) {
  __shared__ __align__(16) char smem[49152];
  unsigned short* AhS = (unsigned short*)smem;            // 128x64
  unsigned short* AlS = (unsigned short*)(smem + 16384);  // 128x64
  unsigned short* WhS = (unsigned short*)(smem + 32768);  //  64x64
  unsigned short* WlS = (unsigned short*)(smem + 40960);  //  64x64
  int o = blockIdx.x;                    // 512 blocks
  int swz = ((o & 7) << 6) | (o >> 3);
  int bn = swz & 7, bm = swz >> 3;       // bn: 64-col group (0..7), bm: 128-row group (0..63)
  const int t = threadIdx.x;
  const int w = t >> 6, l = t & 63;
  const int l15 = l & 15, lg = l >> 4, c7 = l15 & 7;
  const int wr = w >> 1, wc = w & 1;
  const int lrow = l >> 3;
  const int lchunk = (l & 7) ^ lrow;
  const int frag = (lg ^ c7) * 8;
  const unsigned short* Agh = Ah + (size_t)bm * 128 * 512;
  const unsigned short* Agl = Al + (size_t)bm * 128 * 512;
  const unsigned short* Wgh = Wh + (size_t)bn * 64 * 512;
  const unsigned short* Wgl = Wl + (size_t)bn * 64 * 512;
  f32x4 acc[4][2];
#pragma unroll
  for (int m = 0; m < 4; ++m)
#pragma unroll
    for (int n = 0; n < 2; ++n) acc[m][n] = f32x4{0.f, 0.f, 0.f, 0.f};
  for (int kb = 0; kb < 512; kb += 64) {
#pragma unroll
    for (int i = 0; i < 4; ++i) {
      const int seg = w * 4 + i;                       // 16 segs of 8 rows (A: 128 rows)
      const size_t goff = (size_t)(seg * 8 + lrow) * 512 + kb + lchunk * 8;
      gl_lds16(Agh + goff, AhS + seg * 512);
      gl_lds16(Agl + goff, AlS + seg * 512);
    }
#pragma unroll
    for (int i = 0; i < 2; ++i) {
      const int seg = w * 2 + i;                       // 8 segs of 8 rows (W: 64 rows)
      const size_t goff = (size_t)(seg * 8 + lrow) * 512 + kb + lchunk * 8;
      gl_lds16(Wgh + goff, WhS + seg * 512);
      gl_lds16(Wgl + goff, WlS + seg * 512);
    }
    __syncthreads();
#pragma unroll
    for (int ks = 0; ks < 2; ++ks) {
      const int xo = ks ? 32 : 0;
      bf16x8 ah[4], al[4], wh[2], wl[2];
#pragma unroll
      for (int m = 0; m < 4; ++m) {
        const int off = (wr * 64 + m * 16 + l15) * 64 + (frag ^ xo);
        ah[m] = *reinterpret_cast<const bf16x8*>(&AhS[off]);
        al[m] = *reinterpret_cast<const bf16x8*>(&AlS[off]);
      }
#pragma unroll
      for (int n = 0; n < 2; ++n) {
        const int off = (wc * 32 + n * 16 + l15) * 64 + (frag ^ xo);
        wh[n] = *reinterpret_cast<const bf16x8*>(&WhS[off]);
        wl[n] = *reinterpret_cast<const bf16x8*>(&WlS[off]);
      }
#pragma unroll
      for (int m = 0; m < 4; ++m)
#pragma unroll
        for (int n = 0; n < 2; ++n) {
          acc[m][n] = __builtin_amdgcn_mfma_f32_16x16x32_bf16(ah[m], wh[n], acc[m][n], 0, 0, 0);
          acc[m][n] = __builtin_amdgcn_mfma_f32_16x16x32_bf16(al[m], wh[n], acc[m][n], 0, 0, 0);
          acc[m][n] = __builtin_amdgcn_mfma_f32_16x16x32_bf16(ah[m], wl[n], acc[m][n], 0, 0, 0);
        }
    }
    __syncthreads();
  }
  const int row0 = bm * 128 + wr * 64;
  const int col0 = bn * 64 + wc * 32;
#pragma unroll
  for (int m = 0; m < 4; ++m)
#pragma unroll
    for (int n = 0; n < 2; ++n) {
      int col = col0 + n * 16 + l15;
      float bv = bo[col];
#pragma unroll
      for (int r = 0; r < 4; ++r)
        out[(size_t)(row0 + m * 16 + lg * 4 + r) * 512 + col] = acc[m][n][r] + bv;
    }
}

extern "C" void kernel_launch(void* const* d_in, const int* in_sizes, int n_in,
                              void* d_out, int out_size, void* d_ws, size_t ws_size,
                              hipStream_t stream) {
  const float* x_query   = (const float*)d_in[0];
  const float* x_context = (const float*)d_in[1];
  const float* rot_q     = (const float*)d_in[2];
  const float* rot_c     = (const float*)d_in[3];
  const int*   cmask     = (const int*)d_in[4];
  const float* ln_q_g    = (const float*)d_in[5];
  const float* ln_q_b    = (const float*)d_in[6];
  const float* ln_c_g    = (const float*)d_in[7];
  const float* ln_c_b    = (const float*)d_in[8];
  const float* Wq        = (const float*)d_in[9];
  const float* Wkv       = (const float*)d_in[10];
  const float* Wo        = (const float*)d_in[11];
  const float* bo        = (const float*)d_in[12];
  float* out = (float*)d_out;

  char* ws = (char*)d_ws;
  unsigned short* xq_bf = (unsigned short*)(ws + 0);          // 8 MB
  unsigned short* xc_bf = (unsigned short*)(ws + 8388608);    // 16 MB
  unsigned short* Ahb   = (unsigned short*)(ws + 0);          // 8 MB (after projections)
  unsigned short* Alb   = (unsigned short*)(ws + 8388608);    // 8 MB (after proj)
  unsigned short* WqT   = (unsigned short*)(ws + 25165824);   // 0.5 MB
  unsigned short* WkvT  = (unsigned short*)(ws + 25690112);   // 1 MB
  unsigned short* Qb    = (unsigned short*)(ws + 26738688);   // 8 MB
  unsigned short* Kb    = (unsigned short*)(ws + 35127296);   // 16 MB
  unsigned short* VTb   = (unsigned short*)(ws + 51904512);   // 16 MB
  unsigned short* WohT  = (unsigned short*)(ws + 68681728);   // 0.5 MB
  unsigned short* WolT  = (unsigned short*)(ws + 69206016);   // 0.5 MB

  prep_ln<<<dim3(2304), dim3(256), 0, stream>>>(
      Wq, Wkv, Wo, WqT, WkvT, WohT, WolT,
      x_query, x_context, ln_q_g, ln_q_b, ln_c_g, ln_c_b, xq_bf, xc_bf);
  proj_fused<<<dim3(1280), dim3(256), 0, stream>>>(
      xq_bf, xc_bf, WqT, WkvT, rot_q, rot_c, cmask, Qb, Kb, VTb);
  attn_kernel<<<dim3(1024), dim3(256), 0, stream>>>(Qb, Kb, VTb, cmask, rot_q, Ahb, Alb);
  final_gemm<<<dim3(512), dim3(256), 0, stream>>>(Ahb, Alb, WohT, WolT, bo, out);
}